// Round 8
// baseline (493.395 us; speedup 1.0000x reference)
//
#include <hip/hip_runtime.h>
#include <hip/hip_bf16.h>

// Problem constants
#define NN 240        // rows (tokens)
#define CC 6144       // channels
#define DD 3072       // head dim
#define C3 18432      // 3*C
#define HH 2          // heads

typedef __attribute__((ext_vector_type(8))) short bf16x8;
typedef __attribute__((ext_vector_type(4))) float f32x4;
typedef unsigned short ushort_t;

static __device__ __forceinline__ unsigned short f2bf(float f) {
    __hip_bfloat16 h = __float2bfloat16(f);
    return __builtin_bit_cast(unsigned short, h);
}

// global -> LDS direct DMA, 16 B per lane, LDS dest wave-uniform base.
#define GLDS16(g, l) __builtin_amdgcn_global_load_lds( \
    (const __attribute__((address_space(1))) void*)(g), \
    (__attribute__((address_space(3))) void*)(l), 16, 0, 0)

// ---------------------------------------------------------------------------
// gemm_rs: C[240 x N] = A_bf16[256 x K] * B_fp32[N x K]^T (+bias on kc==0).
// R7 structure (passed, absmax 0.0625). Kept as control arm / QK / proj.
// ---------------------------------------------------------------------------
__global__ __launch_bounds__(256, 2)
void gemm_rs(const ushort_t* __restrict__ Ab, int lda, long long sAz,
             const float* __restrict__ B, int ldb, long long sBz,
             const float* __restrict__ bias,
             float* __restrict__ C0, long long sC0z,
             float* __restrict__ CP, long long sCPz,
             int ldc, int N, int Kc, int KS,
             ushort_t* __restrict__ Qb) {
    __shared__ ushort_t sA[2][256 * 64];   // 2 x 32 KB -> 2 blocks/CU

    const int zc = blockIdx.z;
    const int z = zc / KS, kc = zc % KS;
    const ushort_t* Abase = Ab + (size_t)z * sAz + (size_t)kc * Kc;
    const float*    Bbase = B  + (size_t)z * sBz + (size_t)kc * Kc;
    float* Cw = (kc == 0) ? (C0 + (size_t)z * sC0z)
                          : (CP + (size_t)(z * (KS - 1) + kc - 1) * sCPz);

    const int n0 = blockIdx.x * 64;
    const int tid = threadIdx.x, lane = tid & 63, wid = tid >> 6;  // 4 waves
    const int l16 = lane & 15, lk = lane >> 4;

    const ushort_t* ap = Abase + (size_t)(wid * 64 + (lane >> 3)) * lda
                         + ((lane & 7) ^ ((lane >> 3) & 7)) * 8;

    int colc = n0 + wid * 16 + l16; if (colc > N - 1) colc = N - 1;
    const float* bp = Bbase + (size_t)colc * ldb + lk * 8;

    const int nt = Kc / 64;
    f32x4 acc[16] = {};

    auto ISSUE_A = [&](int u, int par) {
        const ushort_t* a = ap + (size_t)u * 64;
        ushort_t* d = &sA[par][wid * 8 * 512];
#pragma unroll
        for (int i = 0; i < 8; ++i)
            GLDS16(a + (size_t)i * 8 * lda, d + i * 512);
    };
    auto LOAD_B4 = [&](int u, float4& b0, float4& b1, float4& b2, float4& b3) {
        const float* p = bp + (size_t)u * 64;
        b0 = *(const float4*)p;
        b1 = *(const float4*)(p + 4);
        b2 = *(const float4*)(p + 32);
        b3 = *(const float4*)(p + 36);
    };
    auto PHASE = [&](int buf, int ph, float4 g0, float4 g1) {
        bf16x8 bfr;
        bfr[0] = (short)f2bf(g0.x); bfr[1] = (short)f2bf(g0.y);
        bfr[2] = (short)f2bf(g0.z); bfr[3] = (short)f2bf(g0.w);
        bfr[4] = (short)f2bf(g1.x); bfr[5] = (short)f2bf(g1.y);
        bfr[6] = (short)f2bf(g1.z); bfr[7] = (short)f2bf(g1.w);
        const char* As = (const char*)sA[buf];
        __builtin_amdgcn_s_setprio(1);
#pragma unroll
        for (int mt = 0; mt < 16; ++mt) {
            int row = mt * 16 + l16;
            int boff = row * 128 + (((ph * 4 + lk) * 16) ^ ((row & 7) << 4));
            bf16x8 af = *(const bf16x8*)(As + boff);
            acc[mt] = __builtin_amdgcn_mfma_f32_16x16x32_bf16(
                af, bfr, acc[mt], 0, 0, 0);
        }
        __builtin_amdgcn_s_setprio(0);
    };

    float4 e0, e1, e2, e3, o0, o1, o2, o3;

    ISSUE_A(0, 0);
    LOAD_B4(0, e0, e1, e2, e3);
    LOAD_B4(nt > 1 ? 1 : 0, o0, o1, o2, o3);
    __builtin_amdgcn_sched_barrier(0);

    auto STEP = [&](int t,
                    float4& r0, float4& r1, float4& r2, float4& r3,
                    float4& w0, float4& w1, float4& w2, float4& w3) {
        asm volatile("s_waitcnt vmcnt(4)" ::: "memory");
        __builtin_amdgcn_s_barrier();
        __builtin_amdgcn_sched_barrier(0);
        int ua = t + 1 < nt ? t + 1 : nt - 1;
        ISSUE_A(ua, (t + 1) & 1);
        __builtin_amdgcn_sched_barrier(0);
        PHASE(t & 1, 0, r0, r1);
        PHASE(t & 1, 1, r2, r3);
        __builtin_amdgcn_sched_barrier(0);
        int ub = t + 2 < nt ? t + 2 : nt - 1;
        LOAD_B4(ub, w0, w1, w2, w3);
        __builtin_amdgcn_sched_barrier(0);
    };

    for (int t = 0; t < nt; t += 2) {
        STEP(t,     e0, e1, e2, e3, e0, e1, e2, e3);
        STEP(t + 1, o0, o1, o2, o3, o0, o1, o2, o3);
    }

#pragma unroll
    for (int mt = 0; mt < 16; ++mt) {
#pragma unroll
        for (int j = 0; j < 4; ++j) {
            int grow = mt * 16 + lk * 4 + j;
            if (grow < NN) {
                int gcol = n0 + wid * 16 + l16;
                if (gcol < N) {
                    float v = acc[mt][j];
                    if (kc == 0 && bias) v += bias[gcol];
                    Cw[(size_t)grow * ldc + gcol] = v;
                    if (Qb && gcol < CC)
                        Qb[(size_t)grow * CC + gcol] = f2bf(v);
                }
            }
        }
    }
}

// ---------------------------------------------------------------------------
// gemm_bb: same structure, but B is PRE-CONVERTED bf16 (L3-resident wqb).
// No cvt in the phase; 2 B-loads/step; per-step wait vmcnt(2). KS=1 only.
// ---------------------------------------------------------------------------
__global__ __launch_bounds__(256, 2)
void gemm_bb(const ushort_t* __restrict__ Ab, int lda,
             const ushort_t* __restrict__ Bb, int ldb,
             float* __restrict__ C0, int ldc, int N, int Kc,
             ushort_t* __restrict__ Qb) {
    __shared__ ushort_t sA[2][256 * 64];

    const int n0 = blockIdx.x * 64;
    const int tid = threadIdx.x, lane = tid & 63, wid = tid >> 6;
    const int l16 = lane & 15, lk = lane >> 4;

    const ushort_t* ap = Ab + (size_t)(wid * 64 + (lane >> 3)) * lda
                         + ((lane & 7) ^ ((lane >> 3) & 7)) * 8;

    int colc = n0 + wid * 16 + l16; if (colc > N - 1) colc = N - 1;
    const ushort_t* bp = Bb + (size_t)colc * ldb + lk * 8;

    const int nt = Kc / 64;
    f32x4 acc[16] = {};

    auto ISSUE_A = [&](int u, int par) {
        const ushort_t* a = ap + (size_t)u * 64;
        ushort_t* d = &sA[par][wid * 8 * 512];
#pragma unroll
        for (int i = 0; i < 8; ++i)
            GLDS16(a + (size_t)i * 8 * lda, d + i * 512);
    };
    auto LOAD_B2 = [&](int u, bf16x8& b0, bf16x8& b1) {
        const ushort_t* p = bp + (size_t)u * 64;
        b0 = *(const bf16x8*)p;           // phase0: k-halfwords lk*8..+8
        b1 = *(const bf16x8*)(p + 32);    // phase1: +32 halfwords
    };
    auto PHASE = [&](int buf, int ph, bf16x8 bfr) {
        const char* As = (const char*)sA[buf];
        __builtin_amdgcn_s_setprio(1);
#pragma unroll
        for (int mt = 0; mt < 16; ++mt) {
            int row = mt * 16 + l16;
            int boff = row * 128 + (((ph * 4 + lk) * 16) ^ ((row & 7) << 4));
            bf16x8 af = *(const bf16x8*)(As + boff);
            acc[mt] = __builtin_amdgcn_mfma_f32_16x16x32_bf16(
                af, bfr, acc[mt], 0, 0, 0);
        }
        __builtin_amdgcn_s_setprio(0);
    };

    bf16x8 e0, e1, o0, o1;

    ISSUE_A(0, 0);
    LOAD_B2(0, e0, e1);
    LOAD_B2(nt > 1 ? 1 : 0, o0, o1);
    __builtin_amdgcn_sched_barrier(0);

    auto STEP = [&](int t, bf16x8& r0, bf16x8& r1, bf16x8& w0, bf16x8& w1) {
        asm volatile("s_waitcnt vmcnt(2)" ::: "memory");
        __builtin_amdgcn_s_barrier();
        __builtin_amdgcn_sched_barrier(0);
        int ua = t + 1 < nt ? t + 1 : nt - 1;
        ISSUE_A(ua, (t + 1) & 1);
        __builtin_amdgcn_sched_barrier(0);
        PHASE(t & 1, 0, r0);
        PHASE(t & 1, 1, r1);
        __builtin_amdgcn_sched_barrier(0);
        int ub = t + 2 < nt ? t + 2 : nt - 1;
        LOAD_B2(ub, w0, w1);
        __builtin_amdgcn_sched_barrier(0);
    };

    for (int t = 0; t < nt; t += 2) {
        STEP(t,     e0, e1, e0, e1);
        STEP(t + 1, o0, o1, o0, o1);
    }

#pragma unroll
    for (int mt = 0; mt < 16; ++mt) {
#pragma unroll
        for (int j = 0; j < 4; ++j) {
            int grow = mt * 16 + lk * 4 + j;
            if (grow < NN) {
                int gcol = n0 + wid * 16 + l16;
                if (gcol < N) {
                    float v = acc[mt][j];
                    Cw_store:
                    C0[(size_t)grow * ldc + gcol] = v;
                    if (Qb && gcol < CC)
                        Qb[(size_t)grow * CC + gcol] = f2bf(v);
                }
            }
        }
    }
}

// ---------------------------------------------------------------------------
// conv_w: linear fp32 -> bf16 stream (the BW probe + weight conversion).
// ---------------------------------------------------------------------------
__global__ __launch_bounds__(256)
void conv_w(const float* __restrict__ w, ushort_t* __restrict__ wb,
            long long n8) {                       // n8 = elems/8
    long long i = (long long)blockIdx.x * 256 + threadIdx.x;
    const long long stride = (long long)gridDim.x * 256;
    for (; i < n8; i += stride) {
        const float* p = w + i * 8;
        float4 a = *(const float4*)p, b = *(const float4*)(p + 4);
        bf16x8 o;
        o[0] = (short)f2bf(a.x); o[1] = (short)f2bf(a.y);
        o[2] = (short)f2bf(a.z); o[3] = (short)f2bf(a.w);
        o[4] = (short)f2bf(b.x); o[5] = (short)f2bf(b.y);
        o[6] = (short)f2bf(b.z); o[7] = (short)f2bf(b.w);
        *(bf16x8*)(wb + i * 8) = o;
    }
}

// xb = bf16(x), rows 240..255 zeroed.
__global__ __launch_bounds__(256)
void convert_kernel(const float* __restrict__ x, ushort_t* __restrict__ xb) {
    int id = blockIdx.x * 256 + threadIdx.x;      // 196608 = 256*6144/8
    int row = id / 768, c8 = id % 768;
    bf16x8 o = {};
    if (row < NN) {
        const float* p = x + (size_t)row * CC + c8 * 8;
        float4 a = *(const float4*)p, b = *(const float4*)(p + 4);
        o[0] = (short)f2bf(a.x); o[1] = (short)f2bf(a.y);
        o[2] = (short)f2bf(a.z); o[3] = (short)f2bf(a.w);
        o[4] = (short)f2bf(b.x); o[5] = (short)f2bf(b.y);
        o[6] = (short)f2bf(b.z); o[7] = (short)f2bf(b.w);
    }
    *(bf16x8*)(xb + (size_t)row * CC + c8 * 8) = o;
}

// out += 2 partials (proj split-K reduce; bias added by kc==0 path)
__global__ __launch_bounds__(256)
void reduce_proj(float4* __restrict__ o4, const float4* __restrict__ p4,
                 long long s4) {
    int i = blockIdx.x * 256 + threadIdx.x;    // 368,640 float4s
    float4 a = o4[i];
#pragma unroll
    for (int k = 0; k < 2; ++k) {
        float4 b = p4[(size_t)k * s4 + i];
        a.x += b.x; a.y += b.y; a.z += b.z; a.w += b.w;
    }
    o4[i] = a;
}

// qmax[(h*240+n)*12 + c] = max over q[h][n][c*256 .. c*256+255]
__global__ __launch_bounds__(256)
void qmax_kernel(const float* __restrict__ qkv, float* __restrict__ qmax) {
    int idx = blockIdx.x * 4 + (threadIdx.x >> 6);   // 0..5759
    int lane = threadIdx.x & 63;
    int c = idx % 12;
    int r = idx / 12;            // h*240 + n
    int n = r % NN, h = r / NN;
    const float* p = qkv + (size_t)n * C3 + h * DD + c * 256 + lane * 4;
    float4 f = *(const float4*)p;
    float m = fmaxf(fmaxf(f.x, f.y), fmaxf(f.z, f.w));
#pragma unroll
    for (int off = 32; off >= 1; off >>= 1)
        m = fmaxf(m, __shfl_xor(m, off));
    if (lane == 0) qmax[idx] = m;
}

// Softmax rows of (scale * (attn + sum partials) + 0.1*Pq), in place.
__global__ __launch_bounds__(256)
void softmax_kernel(float* __restrict__ attn, const float* __restrict__ gpart,
                    int ksm1, const float* __restrict__ qmax) {
    int r = blockIdx.x * 4 + (threadIdx.x >> 6);   // 0..479 = z*240+n
    int lane = threadIdx.x & 63;
    int z = r / NN, n = r % NN;
    float* row = attn + (size_t)r * NN;
    const float* qm = qmax + r * 12;
    const float scale = 0.0180421959f;             // 3072^-0.5
    float v[4];
    float mx = -1e30f;
#pragma unroll
    for (int i = 0; i < 4; ++i) {
        int m = lane + 64 * i;
        v[i] = -1e30f;
        if (m < NN) {
            float s = row[m];
            for (int kc = 0; kc < ksm1; ++kc)
                s += gpart[(size_t)(z * ksm1 + kc) * (NN * NN)
                           + (size_t)n * NN + m];
            v[i] = s * scale + 0.1f * qm[m % 12];
        }
        mx = fmaxf(mx, v[i]);
    }
#pragma unroll
    for (int off = 32; off >= 1; off >>= 1)
        mx = fmaxf(mx, __shfl_xor(mx, off));
    float s = 0.f;
#pragma unroll
    for (int i = 0; i < 4; ++i) {
        v[i] = __expf(v[i] - mx);
        s += v[i];
    }
#pragma unroll
    for (int off = 32; off >= 1; off >>= 1)
        s += __shfl_xor(s, off);
    float inv = 1.0f / s;
#pragma unroll
    for (int i = 0; i < 4; ++i) {
        int m = lane + 64 * i;
        if (m < NN) row[m] = v[i] * inv;
    }
}

// preb[n][h*3072+dd] = bf16( sum_m attn[h][n][m] * v[h][m][dd] )
__global__ __launch_bounds__(256)
void pv_kernel(const float* __restrict__ attn, const float* __restrict__ qkv,
               ushort_t* __restrict__ preb) {
    const int h = blockIdx.z;
    const int n0 = blockIdx.y * 16;
    const int dd0 = blockIdx.x * 256;
    __shared__ float s_attn[16 * NN];
    for (int i = threadIdx.x; i < 16 * NN; i += 256)
        s_attn[i] = attn[(size_t)h * NN * NN + (n0 + i / NN) * NN + (i % NN)];
    __syncthreads();

    const float* vp = qkv + 2 * CC + h * DD + dd0 + threadIdx.x;
    float acc[16] = {};
    for (int m = 0; m < NN; m += 4) {
        float v0 = vp[(size_t)(m + 0) * C3];
        float v1 = vp[(size_t)(m + 1) * C3];
        float v2 = vp[(size_t)(m + 2) * C3];
        float v3 = vp[(size_t)(m + 3) * C3];
#pragma unroll
        for (int i = 0; i < 16; ++i) {
            float4 a = *(const float4*)&s_attn[i * NN + m];
            acc[i] += a.x * v0 + a.y * v1 + a.z * v2 + a.w * v3;
        }
    }
#pragma unroll
    for (int i = 0; i < 16; ++i)
        preb[(size_t)(n0 + i) * CC + h * DD + dd0 + threadIdx.x] =
            f2bf(acc[i]);
}

extern "C" void kernel_launch(void* const* d_in, const int* in_sizes, int n_in,
                              void* d_out, int out_size, void* d_ws, size_t ws_size,
                              hipStream_t stream) {
    const float* x      = (const float*)d_in[0];
    const float* w_qkv  = (const float*)d_in[1];
    const float* w_proj = (const float*)d_in[2];
    const float* b_proj = (const float*)d_in[3];
    float* out = (float*)d_out;

    // ws layout (floats): qkv 4.42M | attn 115K | qmax 5.8K |
    // xb,qb,preb (bf16 256x6144 each = 393K floats each) | gpart 4.42M |
    // wqb (bf16 18432x6144 = 56.6M floats)  => ~272 MB when big path active
    const size_t f_qkv  = (size_t)NN * C3;
    const size_t f_attn = (size_t)HH * NN * NN;
    const size_t f_qmax = (size_t)HH * NN * 12;
    float* qkv   = (float*)d_ws;
    float* attn  = qkv + f_qkv;
    float* qmaxb = attn + f_attn;
    ushort_t* xb   = (ushort_t*)(qmaxb + f_qmax);
    ushort_t* qb   = xb + (size_t)256 * CC;
    ushort_t* preb = qb + (size_t)256 * CC;
    float* gpart = (float*)(preb + (size_t)256 * CC);
    ushort_t* wqb = (ushort_t*)(gpart + f_qkv);

    const size_t base_floats = f_qkv + f_attn + f_qmax
                             + ((size_t)3 * 256 * CC) / 2 + f_qkv;
    const size_t need = (base_floats + (size_t)C3 * CC / 2) * 4;
    const bool big = ws_size >= need;

    // 0. bf16 conversion of x (zero-padded to 256 rows)
    convert_kernel<<<768, 256, 0, stream>>>(x, xb);

    // 1. qkv = x @ w_qkv^T (288 blocks, nt=96; epilogue emits bf16 Q)
    if (big) {
        // Linear-BW probe + weight conversion, then bf16-B GEMM.
        conv_w<<<4096, 256, 0, stream>>>(w_qkv, wqb,
                                         (long long)((size_t)C3 * CC / 8));
        gemm_bb<<<dim3(C3 / 64, 1, 1), 256, 0, stream>>>(
            xb, CC, wqb, CC, qkv, C3, C3, CC, qb);
    } else {
        gemm_rs<<<dim3(C3 / 64, 1, 1), 256, 0, stream>>>(
            xb, CC, 0LL, w_qkv, CC, 0LL, nullptr,
            qkv, 0LL, gpart, 0LL,
            C3, C3, CC, 1, qb);
    }

    // 2. Pq maxpool over q
    qmax_kernel<<<1440, 256, 0, stream>>>(qkv, qmaxb);

    // 3. attn_raw = Q @ K^T per head (KS=24, nt=2: kc0 -> attn, rest -> gpart)
    gemm_rs<<<dim3(4, 1, HH * 24), 256, 0, stream>>>(
        qb, CC, (long long)DD,
        qkv + CC, C3, (long long)DD, nullptr,
        attn, (long long)(NN * NN), gpart, (long long)(NN * NN),
        NN, NN, DD / 24, 24, nullptr);

    // 4. softmax (fuses split-K reduce, scale, +0.1*Pq)
    softmax_kernel<<<120, 256, 0, stream>>>(attn, gpart, 23, qmaxb);

    // 5. preb = bf16(attn @ V)
    pv_kernel<<<dim3(12, 15, HH), 256, 0, stream>>>(attn, qkv, preb);

    // 6. out = pre @ w_proj^T + b_proj (KS=3, nt=32: kc0 -> out+bias)
    //    CONTROL ARM: unchanged fp32-B path for A/B comparison vs gemm_bb.
    gemm_rs<<<dim3(CC / 64, 1, 3), 256, 0, stream>>>(
        preb, CC, 0LL, w_proj, CC, 0LL, b_proj,
        out, 0LL, gpart, (long long)((size_t)NN * CC),
        CC, CC, CC / 3, 3, nullptr);
    reduce_proj<<<1440, 256, 0, stream>>>((float4*)out, (const float4*)gpart,
        (long long)((size_t)NN * CC / 4));
}

// Round 9
// 469.614 us; speedup vs baseline: 1.0506x; 1.0506x over previous
//
#include <hip/hip_runtime.h>
#include <hip/hip_bf16.h>

// Problem constants
#define NN 240        // rows (tokens)
#define CC 6144       // channels
#define DD 3072       // head dim
#define C3 18432      // 3*C
#define HH 2          // heads

typedef __attribute__((ext_vector_type(8))) short bf16x8;
typedef __attribute__((ext_vector_type(4))) float f32x4;
typedef unsigned short ushort_t;

static __device__ __forceinline__ unsigned short f2bf(float f) {
    __hip_bfloat16 h = __float2bfloat16(f);
    return __builtin_bit_cast(unsigned short, h);
}

// global -> LDS direct DMA, 16 B per lane, LDS dest wave-uniform base.
#define GLDS16(g, l) __builtin_amdgcn_global_load_lds( \
    (const __attribute__((address_space(1))) void*)(g), \
    (__attribute__((address_space(3))) void*)(l), 16, 0, 0)

// ---------------------------------------------------------------------------
// gemm_cs: C[240 x N] = A_bf16[256 x K] * B_fp32[N x K]^T (+bias, kc==0).
// ALL loads coalesced via global_load_lds:
//   A: bf16, 8x128B segments/instr, slot l&7 <- source octet (l&7)^(row&7)
//      (proven zero-conflict read layout).
//   B: fp32, 4x256B segments/instr, per col 16 slots of 16B, phys slot l&15
//      <- source k-octet (l&15)^(col&7); read-side 2-way conflict (free).
// BM=256, BN=64, BK=64. 512 threads = 8 waves (4M x 2N), wave tile 64x32.
// A double-buffer + B TRIPLE-buffer LDS (112 KB). Uniform 6 GLDS/wave/step;
// vmcnt(8) at step end == {A(t+1),B(t+1) done}, B never drained to 0.
// ---------------------------------------------------------------------------
__global__ __launch_bounds__(512, 2)
void gemm_cs(const ushort_t* __restrict__ Ab, int lda, long long sAz,
             const float* __restrict__ B, int ldb, long long sBz,
             const float* __restrict__ bias,
             float* __restrict__ C0, long long sC0z,
             float* __restrict__ CP, long long sCPz,
             int ldc, int N, int Kc, int KS,
             ushort_t* __restrict__ Qb) {
    __shared__ ushort_t sA[2][256 * 64];   // 2 x 32 KB
    __shared__ float    sB[3][64 * 64];    // 3 x 16 KB  -> 112 KB total

    const int zc = blockIdx.z;
    const int z = zc / KS, kc = zc % KS;
    const ushort_t* Abase = Ab + (size_t)z * sAz + (size_t)kc * Kc;
    const float*    Bbase = B  + (size_t)z * sBz + (size_t)kc * Kc;
    float* Cw = (kc == 0) ? (C0 + (size_t)z * sC0z)
                          : (CP + (size_t)(z * (KS - 1) + kc - 1) * sCPz);

    const int n0 = blockIdx.x * 64;
    const int tid = threadIdx.x, lane = tid & 63, wid = tid >> 6;  // 8 waves
    const int wm = wid >> 1, wn = wid & 1;     // 4M x 2N
    const int l16 = lane & 15, lk = lane >> 4;

    // A: wave covers rows wid*32..wid*32+31 (4 chunks x 8 rows).
    const ushort_t* ap = Abase + (size_t)(wid * 32 + (lane >> 3)) * lda
                         + ((lane & 7) ^ ((lane >> 3) & 7)) * 8;

    // B: wave covers cols wid*8..wid*8+7 (2 chunks x 4 cols). Lane l ->
    // local col cl = base + (l>>4), phys slot l&15 <- source octet
    // (l&15)^(cl&7). Source offset in floats.
    long long bofs[2];
#pragma unroll
    for (int i = 0; i < 2; ++i) {
        int cl = wid * 8 + i * 4 + (lane >> 4);
        int cg = n0 + cl; if (cg > N - 1) cg = N - 1;
        bofs[i] = (long long)cg * ldb + ((lane & 15) ^ (cl & 7)) * 4;
    }

    const int nt = Kc / 64;
    f32x4 acc[4][2] = {};

    auto ISSUE_A = [&](int t, int par) {     // 4 GLDS
        const ushort_t* a = ap + (size_t)t * 64;
        ushort_t* d = &sA[par][wid * 4 * 512];
#pragma unroll
        for (int i = 0; i < 4; ++i)
            GLDS16(a + (size_t)i * 8 * lda, d + i * 512);
    };
    auto ISSUE_B = [&](int t, int par) {     // 2 GLDS
#pragma unroll
        for (int i = 0; i < 2; ++i)
            GLDS16(Bbase + bofs[i] + (size_t)t * 64,
                   &sB[par][(wid * 8 + i * 4) * 64]);
    };
    auto PHASE = [&](int ab, int bb, int ks) {
        const char* As = (const char*)sA[ab];
        bf16x8 af[4], bfr[2];
#pragma unroll
        for (int mt = 0; mt < 4; ++mt) {
            int row = wm * 64 + mt * 16 + l16;
            af[mt] = *(const bf16x8*)(As + row * 128
                        + (((ks * 4 + lk) * 16) ^ ((row & 7) << 4)));
        }
#pragma unroll
        for (int nf = 0; nf < 2; ++nf) {
            int cl = wn * 32 + nf * 16 + l16;
            int j2 = 2 * (ks * 4 + lk);
            const char* cb = (const char*)(&sB[bb][cl * 64]);
            f32x4 lo = *(const f32x4*)(cb + ((j2 ^ (cl & 7)) * 16));
            f32x4 hi = *(const f32x4*)(cb + (((j2 + 1) ^ (cl & 7)) * 16));
            bf16x8 r;
            r[0] = (short)f2bf(lo[0]); r[1] = (short)f2bf(lo[1]);
            r[2] = (short)f2bf(lo[2]); r[3] = (short)f2bf(lo[3]);
            r[4] = (short)f2bf(hi[0]); r[5] = (short)f2bf(hi[1]);
            r[6] = (short)f2bf(hi[2]); r[7] = (short)f2bf(hi[3]);
            bfr[nf] = r;
        }
        __builtin_amdgcn_s_setprio(1);
#pragma unroll
        for (int mt = 0; mt < 4; ++mt)
#pragma unroll
            for (int nf = 0; nf < 2; ++nf)
                acc[mt][nf] = __builtin_amdgcn_mfma_f32_16x16x32_bf16(
                    af[mt], bfr[nf], acc[mt][nf], 0, 0, 0);
        __builtin_amdgcn_s_setprio(0);
    };

    // Prologue: stage t=0,1 (A,B) and t=2 (B). 14 ops; vmcnt(8) = t0 done.
    ISSUE_A(0, 0);
    ISSUE_B(0, 0);
    ISSUE_A(nt > 1 ? 1 : 0, 1);
    ISSUE_B(nt > 1 ? 1 : 0, 1);
    ISSUE_B(nt > 2 ? 2 : nt - 1, 2 % 3);
    asm volatile("s_waitcnt vmcnt(8)" ::: "memory");
    __builtin_amdgcn_sched_barrier(0);
    __builtin_amdgcn_s_barrier();

    for (int t = 0; t < nt; ++t) {
        PHASE(t & 1, t % 3, 0);
        PHASE(t & 1, t % 3, 1);
        __builtin_amdgcn_s_barrier();          // all waves done reading t's bufs
        __builtin_amdgcn_sched_barrier(0);
        int ta = t + 2 < nt ? t + 2 : nt - 1;  // tail: clamped dummies keep
        int tb = t + 3 < nt ? t + 3 : nt - 1;  // vmcnt accounting uniform
        ISSUE_A(ta, t & 1);
        ISSUE_B(tb, t % 3);
        __builtin_amdgcn_sched_barrier(0);
        // drains A(t+1),B(t+1); keeps B(t+2),A(t+2),B(t+3) (8 ops) in flight
        asm volatile("s_waitcnt vmcnt(8)" ::: "memory");
        __builtin_amdgcn_sched_barrier(0);
        __builtin_amdgcn_s_barrier();
    }

    // Epilogue: fragment row = lk*4+j, col = l16
#pragma unroll
    for (int mt = 0; mt < 4; ++mt) {
#pragma unroll
        for (int j = 0; j < 4; ++j) {
            int grow = wm * 64 + mt * 16 + lk * 4 + j;
            if (grow < NN) {
#pragma unroll
                for (int nf = 0; nf < 2; ++nf) {
                    int gcol = n0 + wn * 32 + nf * 16 + l16;
                    if (gcol < N) {
                        float v = acc[mt][nf][j];
                        if (kc == 0 && bias) v += bias[gcol];
                        Cw[(size_t)grow * ldc + gcol] = v;
                        if (Qb && gcol < CC)
                            Qb[(size_t)grow * CC + gcol] = f2bf(v);
                    }
                }
            }
        }
    }
}

// xb = bf16(x), rows 240..255 zeroed.
__global__ __launch_bounds__(256)
void convert_kernel(const float* __restrict__ x, ushort_t* __restrict__ xb) {
    int id = blockIdx.x * 256 + threadIdx.x;      // 196608 = 256*6144/8
    int row = id / 768, c8 = id % 768;
    bf16x8 o = {};
    if (row < NN) {
        const float* p = x + (size_t)row * CC + c8 * 8;
        float4 a = *(const float4*)p, b = *(const float4*)(p + 4);
        o[0] = (short)f2bf(a.x); o[1] = (short)f2bf(a.y);
        o[2] = (short)f2bf(a.z); o[3] = (short)f2bf(a.w);
        o[4] = (short)f2bf(b.x); o[5] = (short)f2bf(b.y);
        o[6] = (short)f2bf(b.z); o[7] = (short)f2bf(b.w);
    }
    *(bf16x8*)(xb + (size_t)row * CC + c8 * 8) = o;
}

// out += 2 partials (proj split-K reduce; bias added by kc==0 path)
__global__ __launch_bounds__(256)
void reduce_proj(float4* __restrict__ o4, const float4* __restrict__ p4,
                 long long s4) {
    int i = blockIdx.x * 256 + threadIdx.x;    // 368,640 float4s
    float4 a = o4[i];
#pragma unroll
    for (int k = 0; k < 2; ++k) {
        float4 b = p4[(size_t)k * s4 + i];
        a.x += b.x; a.y += b.y; a.z += b.z; a.w += b.w;
    }
    o4[i] = a;
}

// qmax[(h*240+n)*12 + c] = max over q[h][n][c*256 .. c*256+255]
__global__ __launch_bounds__(256)
void qmax_kernel(const float* __restrict__ qkv, float* __restrict__ qmax) {
    int idx = blockIdx.x * 4 + (threadIdx.x >> 6);   // 0..5759
    int lane = threadIdx.x & 63;
    int c = idx % 12;
    int r = idx / 12;            // h*240 + n
    int n = r % NN, h = r / NN;
    const float* p = qkv + (size_t)n * C3 + h * DD + c * 256 + lane * 4;
    float4 f = *(const float4*)p;
    float m = fmaxf(fmaxf(f.x, f.y), fmaxf(f.z, f.w));
#pragma unroll
    for (int off = 32; off >= 1; off >>= 1)
        m = fmaxf(m, __shfl_xor(m, off));
    if (lane == 0) qmax[idx] = m;
}

// Softmax rows of (scale * (attn + sum partials) + 0.1*Pq), in place.
__global__ __launch_bounds__(256)
void softmax_kernel(float* __restrict__ attn, const float* __restrict__ gpart,
                    int ksm1, const float* __restrict__ qmax) {
    int r = blockIdx.x * 4 + (threadIdx.x >> 6);   // 0..479 = z*240+n
    int lane = threadIdx.x & 63;
    int z = r / NN, n = r % NN;
    float* row = attn + (size_t)r * NN;
    const float* qm = qmax + r * 12;
    const float scale = 0.0180421959f;             // 3072^-0.5
    float v[4];
    float mx = -1e30f;
#pragma unroll
    for (int i = 0; i < 4; ++i) {
        int m = lane + 64 * i;
        v[i] = -1e30f;
        if (m < NN) {
            float s = row[m];
            for (int kc = 0; kc < ksm1; ++kc)
                s += gpart[(size_t)(z * ksm1 + kc) * (NN * NN)
                           + (size_t)n * NN + m];
            v[i] = s * scale + 0.1f * qm[m % 12];
        }
        mx = fmaxf(mx, v[i]);
    }
#pragma unroll
    for (int off = 32; off >= 1; off >>= 1)
        mx = fmaxf(mx, __shfl_xor(mx, off));
    float s = 0.f;
#pragma unroll
    for (int i = 0; i < 4; ++i) {
        v[i] = __expf(v[i] - mx);
        s += v[i];
    }
#pragma unroll
    for (int off = 32; off >= 1; off >>= 1)
        s += __shfl_xor(s, off);
    float inv = 1.0f / s;
#pragma unroll
    for (int i = 0; i < 4; ++i) {
        int m = lane + 64 * i;
        if (m < NN) row[m] = v[i] * inv;
    }
}

// preb[n][h*3072+dd] = bf16( sum_m attn[h][n][m] * v[h][m][dd] )
__global__ __launch_bounds__(256)
void pv_kernel(const float* __restrict__ attn, const float* __restrict__ qkv,
               ushort_t* __restrict__ preb) {
    const int h = blockIdx.z;
    const int n0 = blockIdx.y * 16;
    const int dd0 = blockIdx.x * 256;
    __shared__ float s_attn[16 * NN];
    for (int i = threadIdx.x; i < 16 * NN; i += 256)
        s_attn[i] = attn[(size_t)h * NN * NN + (n0 + i / NN) * NN + (i % NN)];
    __syncthreads();

    const float* vp = qkv + 2 * CC + h * DD + dd0 + threadIdx.x;
    float acc[16] = {};
    for (int m = 0; m < NN; m += 4) {
        float v0 = vp[(size_t)(m + 0) * C3];
        float v1 = vp[(size_t)(m + 1) * C3];
        float v2 = vp[(size_t)(m + 2) * C3];
        float v3 = vp[(size_t)(m + 3) * C3];
#pragma unroll
        for (int i = 0; i < 16; ++i) {
            float4 a = *(const float4*)&s_attn[i * NN + m];
            acc[i] += a.x * v0 + a.y * v1 + a.z * v2 + a.w * v3;
        }
    }
#pragma unroll
    for (int i = 0; i < 16; ++i)
        preb[(size_t)(n0 + i) * CC + h * DD + dd0 + threadIdx.x] =
            f2bf(acc[i]);
}

extern "C" void kernel_launch(void* const* d_in, const int* in_sizes, int n_in,
                              void* d_out, int out_size, void* d_ws, size_t ws_size,
                              hipStream_t stream) {
    const float* x      = (const float*)d_in[0];
    const float* w_qkv  = (const float*)d_in[1];
    const float* w_proj = (const float*)d_in[2];
    const float* b_proj = (const float*)d_in[3];
    float* out = (float*)d_out;

    // ws layout (floats): qkv 4.42M | attn 115K | qmax 5.8K |
    // xb,qb,preb (bf16 256x6144 each) | gpart 4.42M   => ~45.3 MB
    const size_t f_qkv  = (size_t)NN * C3;
    const size_t f_attn = (size_t)HH * NN * NN;
    const size_t f_qmax = (size_t)HH * NN * 12;
    float* qkv   = (float*)d_ws;
    float* attn  = qkv + f_qkv;
    float* qmaxb = attn + f_attn;
    ushort_t* xb   = (ushort_t*)(qmaxb + f_qmax);
    ushort_t* qb   = xb + (size_t)256 * CC;
    ushort_t* preb = qb + (size_t)256 * CC;
    float* gpart = (float*)(preb + (size_t)256 * CC);

    // 0. bf16 conversion of x (zero-padded to 256 rows)
    convert_kernel<<<768, 256, 0, stream>>>(x, xb);

    // 1. qkv = x @ w_qkv^T  (288 blocks, nt=96; epilogue emits bf16 Q)
    gemm_cs<<<dim3(C3 / 64, 1, 1), 512, 0, stream>>>(
        xb, CC, 0LL, w_qkv, CC, 0LL, nullptr,
        qkv, 0LL, gpart, 0LL,
        C3, C3, CC, 1, qb);

    // 2. Pq maxpool over q
    qmax_kernel<<<1440, 256, 0, stream>>>(qkv, qmaxb);

    // 3. attn_raw = Q @ K^T per head (KS=24, nt=2: kc0 -> attn, rest -> gpart)
    gemm_cs<<<dim3(4, 1, HH * 24), 512, 0, stream>>>(
        qb, CC, (long long)DD,
        qkv + CC, C3, (long long)DD, nullptr,
        attn, (long long)(NN * NN), gpart, (long long)(NN * NN),
        NN, NN, DD / 24, 24, nullptr);

    // 4. softmax (fuses split-K reduce, scale, +0.1*Pq)
    softmax_kernel<<<120, 256, 0, stream>>>(attn, gpart, 23, qmaxb);

    // 5. preb = bf16(attn @ V)
    pv_kernel<<<dim3(12, 15, HH), 256, 0, stream>>>(attn, qkv, preb);

    // 6. out = pre @ w_proj^T + b_proj (KS=3, nt=32: kc0 -> out+bias)
    gemm_cs<<<dim3(CC / 64, 1, 3), 512, 0, stream>>>(
        preb, CC, 0LL, w_proj, CC, 0LL, b_proj,
        out, 0LL, gpart, (long long)((size_t)NN * CC),
        CC, CC, CC / 3, 3, nullptr);
    reduce_proj<<<1440, 256, 0, stream>>>((float4*)out, (const float4*)gpart,
        (long long)((size_t)NN * CC / 4));
}

// Round 10
// 380.386 us; speedup vs baseline: 1.2971x; 1.2346x over previous
//
#include <hip/hip_runtime.h>
#include <hip/hip_bf16.h>

// Problem constants
#define NN 240        // rows (tokens)
#define CC 6144       // channels
#define DD 3072       // head dim
#define C3 18432      // 3*C
#define HH 2          // heads

typedef __attribute__((ext_vector_type(8))) short bf16x8;
typedef __attribute__((ext_vector_type(4))) float f32x4;
typedef unsigned short ushort_t;

static __device__ __forceinline__ unsigned short f2bf(float f) {
    __hip_bfloat16 h = __float2bfloat16(f);
    return __builtin_bit_cast(unsigned short, h);
}

// global -> LDS direct DMA, 16 B per lane, LDS dest wave-uniform base.
#define GLDS16(g, l) __builtin_amdgcn_global_load_lds( \
    (const __attribute__((address_space(1))) void*)(g), \
    (__attribute__((address_space(3))) void*)(l), 16, 0, 0)

// ---------------------------------------------------------------------------
// gemm_t: C[240 x N] = A_bf16[256 x K] * B_fp32[N x K]^T (+bias on kc==0).
// m97-shaped: BM=256, BN=128, BK=32, 256 threads (4 waves, 4M x 1N),
// LDS 64 KB -> 2 blocks/CU, deep split-K grids for TLP.
// Wave tile 64 rows x 128 cols: acc[4][8] (128 VGPR).
// LDS layouts (derived, <=2-way conflict = free):
//   A: [row][32 bf16] rows of 64 B; read slot = lk ^ ((row>>1)&3)
//   B: [col][32 f32] cols of 128 B; read quad = q ^ (col&7)
// Both staged by global_load_lds with pre-swizzled SOURCE (LDS linear).
// Per step: issue 8 GLDS (next tile) -> vmcnt(8) -> barrier -> 32 MFMA/wave
// -> barrier. vmcnt never drained to 0 in the loop.
// ---------------------------------------------------------------------------
__global__ __launch_bounds__(256, 2)
void gemm_t(const ushort_t* __restrict__ Ab, int lda, long long sAz,
            const float* __restrict__ B, int ldb, long long sBz,
            const float* __restrict__ bias,
            float* __restrict__ C0, long long sC0z,
            float* __restrict__ CP, long long sCPz,
            int ldc, int N, int Kc, int KS) {
    __shared__ ushort_t sA[2][256 * 32];   // 2 x 16 KB
    __shared__ float    sB[2][128 * 32];   // 2 x 16 KB  -> 64 KB total

    const int zc = blockIdx.z;
    const int z = zc / KS, kc = zc % KS;
    const ushort_t* Abase = Ab + (size_t)z * sAz + (size_t)kc * Kc;
    const float*    Bbase = B  + (size_t)z * sBz + (size_t)kc * Kc;
    float* Cw = (kc == 0) ? (C0 + (size_t)z * sC0z)
                          : (CP + (size_t)(z * (KS - 1) + kc - 1) * sCPz);

    const int n0 = blockIdx.x * 128;
    const int tid = threadIdx.x, lane = tid & 63, wid = tid >> 6;  // 4 waves
    const int l16 = lane & 15, lk = lane >> 4;

    // A staging: instr i covers rows (wid*4+i)*16..+15 (16 rows x 64 B = 1 KB).
    // Lane l -> row +(l>>2), phys 16B-slot l&3 <- source k-oct (l&3)^((l>>3)&3)
    // (inverse of read swizzle lk ^ ((row>>1)&3); row base % 8 == 0).
    const int ar = lane >> 2;
    const int akoct = (lane & 3) ^ ((lane >> 3) & 3);

    // B staging: instr i covers cols (wid*4+i)*8..+7 (8 cols x 128 B = 1 KB).
    // Lane l -> col +(l>>3), phys slot l&7 <- source k-quad (l&7)^((l>>3)&7).
    long long bofs[4];
#pragma unroll
    for (int i = 0; i < 4; ++i) {
        int cl = (wid * 4 + i) * 8 + (lane >> 3);
        int cg = n0 + cl; if (cg > N - 1) cg = N - 1;
        bofs[i] = (long long)cg * ldb + ((lane & 7) ^ ((lane >> 3) & 7)) * 4;
    }

    const int nt = Kc / 32;
    f32x4 acc[4][8] = {};

    auto ISSUE = [&](int t, int par) {        // 4 A + 4 B GLDS
        ushort_t* sa = par ? sA[1] : sA[0];
        float*    sb = par ? sB[1] : sB[0];
#pragma unroll
        for (int i = 0; i < 4; ++i) {
            int rb = (wid * 4 + i) * 16;
            GLDS16(Abase + (size_t)(rb + ar) * lda + akoct * 8 + (size_t)t * 32,
                   sa + rb * 32);
        }
#pragma unroll
        for (int i = 0; i < 4; ++i) {
            int cb = (wid * 4 + i) * 8;
            GLDS16(Bbase + bofs[i] + (size_t)t * 32, sb + cb * 32);
        }
    };

    auto COMPUTE = [&](int par) {
        const char* As = par ? (const char*)sA[1] : (const char*)sA[0];
        const char* Bs = par ? (const char*)sB[1] : (const char*)sB[0];
        bf16x8 af[4];
#pragma unroll
        for (int mt = 0; mt < 4; ++mt) {
            int r = wid * 64 + mt * 16 + l16;
            af[mt] = *(const bf16x8*)(As + r * 64
                        + ((lk ^ ((r >> 1) & 3)) * 16));
        }
#pragma unroll
        for (int nf = 0; nf < 8; ++nf) {
            int c = nf * 16 + l16;
            const char* cb = Bs + c * 128;
            f32x4 lo = *(const f32x4*)(cb + (((2 * lk) ^ (c & 7)) * 16));
            f32x4 hi = *(const f32x4*)(cb + (((2 * lk + 1) ^ (c & 7)) * 16));
            bf16x8 r;
            r[0] = (short)f2bf(lo[0]); r[1] = (short)f2bf(lo[1]);
            r[2] = (short)f2bf(lo[2]); r[3] = (short)f2bf(lo[3]);
            r[4] = (short)f2bf(hi[0]); r[5] = (short)f2bf(hi[1]);
            r[6] = (short)f2bf(hi[2]); r[7] = (short)f2bf(hi[3]);
            __builtin_amdgcn_s_setprio(1);
#pragma unroll
            for (int mt = 0; mt < 4; ++mt)
                acc[mt][nf] = __builtin_amdgcn_mfma_f32_16x16x32_bf16(
                    af[mt], r, acc[mt][nf], 0, 0, 0);
            __builtin_amdgcn_s_setprio(0);
        }
    };

    ISSUE(0, 0);
    for (int t = 0; t < nt; ++t) {
        int tn = (t + 1 < nt) ? t + 1 : t;    // tail: dummy keeps counts uniform
        ISSUE(tn, (t + 1) & 1);
        asm volatile("s_waitcnt vmcnt(8)" ::: "memory");   // tile t landed
        __builtin_amdgcn_sched_barrier(0);
        __builtin_amdgcn_s_barrier();
        COMPUTE(t & 1);
        __builtin_amdgcn_sched_barrier(0);
        __builtin_amdgcn_s_barrier();         // all waves done reading buf t&1
    }

    // Epilogue: fragment row = lk*4+j (within mt*16), col = nf*16 + l16
#pragma unroll
    for (int mt = 0; mt < 4; ++mt) {
#pragma unroll
        for (int j = 0; j < 4; ++j) {
            int grow = wid * 64 + mt * 16 + lk * 4 + j;
            if (grow < NN) {
#pragma unroll
                for (int nf = 0; nf < 8; ++nf) {
                    int gcol = n0 + nf * 16 + l16;
                    if (gcol < N) {
                        float v = acc[mt][nf][j];
                        if (kc == 0 && bias) v += bias[gcol];
                        Cw[(size_t)grow * ldc + gcol] = v;
                    }
                }
            }
        }
    }
}

// xb = bf16(x), rows 240..255 zeroed.
__global__ __launch_bounds__(256)
void convert_kernel(const float* __restrict__ x, ushort_t* __restrict__ xb) {
    int id = blockIdx.x * 256 + threadIdx.x;      // 196608 = 256*6144/8
    int row = id / 768, c8 = id % 768;
    bf16x8 o = {};
    if (row < NN) {
        const float* p = x + (size_t)row * CC + c8 * 8;
        float4 a = *(const float4*)p, b = *(const float4*)(p + 4);
        o[0] = (short)f2bf(a.x); o[1] = (short)f2bf(a.y);
        o[2] = (short)f2bf(a.z); o[3] = (short)f2bf(a.w);
        o[4] = (short)f2bf(b.x); o[5] = (short)f2bf(b.y);
        o[6] = (short)f2bf(b.z); o[7] = (short)f2bf(b.w);
    }
    *(bf16x8*)(xb + (size_t)row * CC + c8 * 8) = o;
}

// qkv += 3 partials (in place); emit bf16 Q (cols < 6144).
__global__ __launch_bounds__(256)
void reduce_qkv(float4* __restrict__ q4, const float4* __restrict__ p4,
                long long s4, ushort_t* __restrict__ qb) {
    int i = blockIdx.x * 256 + threadIdx.x;     // 1,105,920 float4s
    float4 a = q4[i];
#pragma unroll
    for (int k = 0; k < 3; ++k) {
        float4 b = p4[(size_t)k * s4 + i];
        a.x += b.x; a.y += b.y; a.z += b.z; a.w += b.w;
    }
    q4[i] = a;
    int row = i / 4608, c4 = i % 4608;
    if (c4 < 1536) {
        ushort4 u;
        u.x = f2bf(a.x); u.y = f2bf(a.y); u.z = f2bf(a.z); u.w = f2bf(a.w);
        *(ushort4*)(qb + (size_t)row * CC + c4 * 4) = u;
    }
}

// out += 11 partials (bias added by kc==0 epilogue)
__global__ __launch_bounds__(256)
void reduce_proj(float4* __restrict__ o4, const float4* __restrict__ p4,
                 long long s4) {
    int i = blockIdx.x * 256 + threadIdx.x;    // 368,640 float4s
    float4 a = o4[i];
#pragma unroll
    for (int k = 0; k < 11; ++k) {
        float4 b = p4[(size_t)k * s4 + i];
        a.x += b.x; a.y += b.y; a.z += b.z; a.w += b.w;
    }
    o4[i] = a;
}

// qmax[(h*240+n)*12 + c] = max over q[h][n][c*256 .. c*256+255]
__global__ __launch_bounds__(256)
void qmax_kernel(const float* __restrict__ qkv, float* __restrict__ qmax) {
    int idx = blockIdx.x * 4 + (threadIdx.x >> 6);   // 0..5759
    int lane = threadIdx.x & 63;
    int c = idx % 12;
    int r = idx / 12;            // h*240 + n
    int n = r % NN, h = r / NN;
    const float* p = qkv + (size_t)n * C3 + h * DD + c * 256 + lane * 4;
    float4 f = *(const float4*)p;
    float m = fmaxf(fmaxf(f.x, f.y), fmaxf(f.z, f.w));
#pragma unroll
    for (int off = 32; off >= 1; off >>= 1)
        m = fmaxf(m, __shfl_xor(m, off));
    if (lane == 0) qmax[idx] = m;
}

// Softmax rows of (scale * (attn + sum partials) + 0.1*Pq), in place.
__global__ __launch_bounds__(256)
void softmax_kernel(float* __restrict__ attn, const float* __restrict__ gpart,
                    int ksm1, const float* __restrict__ qmax) {
    int r = blockIdx.x * 4 + (threadIdx.x >> 6);   // 0..479 = z*240+n
    int lane = threadIdx.x & 63;
    int z = r / NN, n = r % NN;
    float* row = attn + (size_t)r * NN;
    const float* qm = qmax + r * 12;
    const float scale = 0.0180421959f;             // 3072^-0.5
    float v[4];
    float mx = -1e30f;
#pragma unroll
    for (int i = 0; i < 4; ++i) {
        int m = lane + 64 * i;
        v[i] = -1e30f;
        if (m < NN) {
            float s = row[m];
            for (int kc = 0; kc < ksm1; ++kc)
                s += gpart[(size_t)(z * ksm1 + kc) * (NN * NN)
                           + (size_t)n * NN + m];
            v[i] = s * scale + 0.1f * qm[m % 12];
        }
        mx = fmaxf(mx, v[i]);
    }
#pragma unroll
    for (int off = 32; off >= 1; off >>= 1)
        mx = fmaxf(mx, __shfl_xor(mx, off));
    float s = 0.f;
#pragma unroll
    for (int i = 0; i < 4; ++i) {
        v[i] = __expf(v[i] - mx);
        s += v[i];
    }
#pragma unroll
    for (int off = 32; off >= 1; off >>= 1)
        s += __shfl_xor(s, off);
    float inv = 1.0f / s;
#pragma unroll
    for (int i = 0; i < 4; ++i) {
        int m = lane + 64 * i;
        if (m < NN) row[m] = v[i] * inv;
    }
}

// preb[n][h*3072+dd] = bf16( sum_m attn[h][n][m] * v[h][m][dd] )
__global__ __launch_bounds__(256)
void pv_kernel(const float* __restrict__ attn, const float* __restrict__ qkv,
               ushort_t* __restrict__ preb) {
    const int h = blockIdx.z;
    const int n0 = blockIdx.y * 16;
    const int dd0 = blockIdx.x * 256;
    __shared__ float s_attn[16 * NN];
    for (int i = threadIdx.x; i < 16 * NN; i += 256)
        s_attn[i] = attn[(size_t)h * NN * NN + (n0 + i / NN) * NN + (i % NN)];
    __syncthreads();

    const float* vp = qkv + 2 * CC + h * DD + dd0 + threadIdx.x;
    float acc[16] = {};
    for (int m = 0; m < NN; m += 4) {
        float v0 = vp[(size_t)(m + 0) * C3];
        float v1 = vp[(size_t)(m + 1) * C3];
        float v2 = vp[(size_t)(m + 2) * C3];
        float v3 = vp[(size_t)(m + 3) * C3];
#pragma unroll
        for (int i = 0; i < 16; ++i) {
            float4 a = *(const float4*)&s_attn[i * NN + m];
            acc[i] += a.x * v0 + a.y * v1 + a.z * v2 + a.w * v3;
        }
    }
#pragma unroll
    for (int i = 0; i < 16; ++i)
        preb[(size_t)(n0 + i) * CC + h * DD + dd0 + threadIdx.x] =
            f2bf(acc[i]);
}

extern "C" void kernel_launch(void* const* d_in, const int* in_sizes, int n_in,
                              void* d_out, int out_size, void* d_ws, size_t ws_size,
                              hipStream_t stream) {
    const float* x      = (const float*)d_in[0];
    const float* w_qkv  = (const float*)d_in[1];
    const float* w_proj = (const float*)d_in[2];
    const float* b_proj = (const float*)d_in[3];
    float* out = (float*)d_out;

    // ws layout (floats): qkv 4.42M | attn 115K | qmax 5.8K |
    // xb,qb,preb (bf16 256x6144 each) | gpart 16.3M  => ~93 MB
    // (R8 proved ws >= 272 MB: its "big" branch executed.)
    const size_t f_qkv  = (size_t)NN * C3;       // 4,423,680
    const size_t f_attn = (size_t)HH * NN * NN;
    const size_t f_qmax = (size_t)HH * NN * 12;
    const size_t f_pre  = (size_t)NN * CC;       // 1,474,560
    float* qkv   = (float*)d_ws;
    float* attn  = qkv + f_qkv;
    float* qmaxb = attn + f_attn;
    ushort_t* xb   = (ushort_t*)(qmaxb + f_qmax);
    ushort_t* qb   = xb + (size_t)256 * CC;
    ushort_t* preb = qb + (size_t)256 * CC;
    float* gpart = (float*)(preb + (size_t)256 * CC);

    // 0. bf16 conversion of x (zero-padded to 256 rows)
    convert_kernel<<<768, 256, 0, stream>>>(x, xb);

    // 1. qkv = x @ w_qkv^T  (KS=4, 576 blocks, Kc=1536, nt=48)
    gemm_t<<<dim3(C3 / 128, 1, 4), 256, 0, stream>>>(
        xb, CC, 0LL, w_qkv, CC, 0LL, nullptr,
        qkv, 0LL, gpart, (long long)f_qkv,
        C3, C3, CC / 4, 4);
    reduce_qkv<<<4320, 256, 0, stream>>>((float4*)qkv, (const float4*)gpart,
        (long long)(f_qkv / 4), qb);

    // 2. Pq maxpool over q
    qmax_kernel<<<1440, 256, 0, stream>>>(qkv, qmaxb);

    // 3. attn_raw = Q @ K^T per head (KS=24, 96 blocks, Kc=128, nt=4)
    gemm_t<<<dim3(2, 1, HH * 24), 256, 0, stream>>>(
        qb, CC, (long long)DD,
        qkv + CC, C3, (long long)DD, nullptr,
        attn, (long long)(NN * NN), gpart, (long long)(NN * NN),
        NN, NN, DD / 24, 24);

    // 4. softmax (fuses split-K reduce, scale, +0.1*Pq)
    softmax_kernel<<<120, 256, 0, stream>>>(attn, gpart, 23, qmaxb);

    // 5. preb = bf16(attn @ V)
    pv_kernel<<<dim3(12, 15, HH), 256, 0, stream>>>(attn, qkv, preb);

    // 6. out = pre @ w_proj^T + b_proj (KS=12, 576 blocks, Kc=512, nt=16)
    gemm_t<<<dim3(CC / 128, 1, 12), 256, 0, stream>>>(
        preb, CC, 0LL, w_proj, CC, 0LL, b_proj,
        out, 0LL, gpart, (long long)f_pre,
        CC, CC, CC / 12, 12);
    reduce_proj<<<1440, 256, 0, stream>>>((float4*)out, (const float4*)gpart,
        (long long)(f_pre / 4));
}

// Round 11
// 369.022 us; speedup vs baseline: 1.3370x; 1.0308x over previous
//
#include <hip/hip_runtime.h>
#include <hip/hip_bf16.h>

// Problem constants
#define NN 240        // rows (tokens)
#define CC 6144       // channels
#define DD 3072       // head dim
#define C3 18432      // 3*C
#define HH 2          // heads

typedef __attribute__((ext_vector_type(8))) short bf16x8;
typedef __attribute__((ext_vector_type(4))) float f32x4;
typedef unsigned short ushort_t;

static __device__ __forceinline__ unsigned short f2bf(float f) {
    __hip_bfloat16 h = __float2bfloat16(f);
    return __builtin_bit_cast(unsigned short, h);
}

// global -> LDS direct DMA, 16 B per lane, LDS dest wave-uniform base.
#define GLDS16(g, l) __builtin_amdgcn_global_load_lds( \
    (const __attribute__((address_space(1))) void*)(g), \
    (__attribute__((address_space(3))) void*)(l), 16, 0, 0)

// ---------------------------------------------------------------------------
// gemm_m97: C[240 x N] = A_bf16[256 x K] * B_fp32[N x K]^T (+bias, kc==0).
// m97-recipe clone: BM=256, BN=64, BK=32, 256 threads (4 waves, 4M x 1N,
// wave tile 64x64, acc[4][4]), SINGLE-buffered 24 KB LDS, plain
// __syncthreads() per step (compiler-emitted vmcnt drain), 4 blocks/CU
// (16 waves/CU) so co-resident independent barrier groups cover the drain
// stalls (m97/m114 mechanism). Deep split-K grids keep all CUs fed.
// LDS layouts (proven in R10, <=2-way conflict = free):
//   A: [row][32 bf16] rows of 64 B; read slot = lk ^ ((row>>1)&3)
//   B: [col][32 f32] cols of 128 B; read quad = q ^ (col&7)
// Both staged by global_load_lds with pre-swizzled SOURCE (LDS linear).
// ---------------------------------------------------------------------------
__global__ __launch_bounds__(256, 4)
void gemm_m97(const ushort_t* __restrict__ Ab, int lda, long long sAz,
              const float* __restrict__ B, int ldb, long long sBz,
              const float* __restrict__ bias,
              float* __restrict__ C0, long long sC0z,
              float* __restrict__ CP, long long sCPz,
              int ldc, int N, int Kc, int KS) {
    __shared__ ushort_t sA[256 * 32];   // 16 KB
    __shared__ float    sB[64 * 32];    //  8 KB  -> 24 KB total

    const int zc = blockIdx.z;
    const int z = zc / KS, kc = zc % KS;
    const ushort_t* Abase = Ab + (size_t)z * sAz + (size_t)kc * Kc;
    const float*    Bbase = B  + (size_t)z * sBz + (size_t)kc * Kc;
    float* Cw = (kc == 0) ? (C0 + (size_t)z * sC0z)
                          : (CP + (size_t)(z * (KS - 1) + kc - 1) * sCPz);

    const int n0 = blockIdx.x * 64;
    const int tid = threadIdx.x, lane = tid & 63, wid = tid >> 6;  // 4 waves
    const int l16 = lane & 15, lk = lane >> 4;

    // A staging: instr i covers rows (wid*4+i)*16..+15 (16 rows x 64 B = 1 KB).
    // Lane l -> row +(l>>2), phys 16B-slot l&3 <- source k-oct (l&3)^((l>>3)&3)
    // (inverse of read swizzle lk ^ ((row>>1)&3); row base % 8 == 0).
    const int ar = lane >> 2;
    const int akoct = (lane & 3) ^ ((lane >> 3) & 3);

    // B staging: instr i covers cols (wid*2+i)*8..+7 (8 cols x 128 B = 1 KB).
    // Lane l -> col +(l>>3), phys slot l&7 <- source k-quad (l&7)^((l>>3)&7).
    long long bofs[2];
#pragma unroll
    for (int i = 0; i < 2; ++i) {
        int cl = (wid * 2 + i) * 8 + (lane >> 3);
        int cg = n0 + cl; if (cg > N - 1) cg = N - 1;
        bofs[i] = (long long)cg * ldb + ((lane & 7) ^ ((lane >> 3) & 7)) * 4;
    }

    const int nt = Kc / 32;
    f32x4 acc[4][4] = {};

    for (int t = 0; t < nt; ++t) {
        // stage tile t (6 GLDS per wave)
#pragma unroll
        for (int i = 0; i < 4; ++i) {
            int rb = (wid * 4 + i) * 16;
            GLDS16(Abase + (size_t)(rb + ar) * lda + akoct * 8 + (size_t)t * 32,
                   sA + rb * 32);
        }
#pragma unroll
        for (int i = 0; i < 2; ++i) {
            int cb = (wid * 2 + i) * 8;
            GLDS16(Bbase + bofs[i] + (size_t)t * 32, sB + cb * 32);
        }
        __syncthreads();   // compiler emits vmcnt(0) drain + s_barrier (m97)

        // compute tile t
        bf16x8 af[4];
#pragma unroll
        for (int mt = 0; mt < 4; ++mt) {
            int r = wid * 64 + mt * 16 + l16;
            af[mt] = *(const bf16x8*)((const char*)sA + r * 64
                        + ((lk ^ ((r >> 1) & 3)) * 16));
        }
#pragma unroll
        for (int nf = 0; nf < 4; ++nf) {
            int c = nf * 16 + l16;
            const char* cb = (const char*)sB + c * 128;
            f32x4 lo = *(const f32x4*)(cb + (((2 * lk) ^ (c & 7)) * 16));
            f32x4 hi = *(const f32x4*)(cb + (((2 * lk + 1) ^ (c & 7)) * 16));
            bf16x8 r;
            r[0] = (short)f2bf(lo[0]); r[1] = (short)f2bf(lo[1]);
            r[2] = (short)f2bf(lo[2]); r[3] = (short)f2bf(lo[3]);
            r[4] = (short)f2bf(hi[0]); r[5] = (short)f2bf(hi[1]);
            r[6] = (short)f2bf(hi[2]); r[7] = (short)f2bf(hi[3]);
#pragma unroll
            for (int mt = 0; mt < 4; ++mt)
                acc[mt][nf] = __builtin_amdgcn_mfma_f32_16x16x32_bf16(
                    af[mt], r, acc[mt][nf], 0, 0, 0);
        }
        __syncthreads();   // protect single buffer before next stage
    }

    // Epilogue: fragment row = lk*4+j, col = nf*16 + l16
#pragma unroll
    for (int mt = 0; mt < 4; ++mt) {
#pragma unroll
        for (int j = 0; j < 4; ++j) {
            int grow = wid * 64 + mt * 16 + lk * 4 + j;
            if (grow < NN) {
#pragma unroll
                for (int nf = 0; nf < 4; ++nf) {
                    int gcol = n0 + nf * 16 + l16;
                    if (gcol < N) {
                        float v = acc[mt][nf][j];
                        if (kc == 0 && bias) v += bias[gcol];
                        Cw[(size_t)grow * ldc + gcol] = v;
                    }
                }
            }
        }
    }
}

// xb = bf16(x), rows 240..255 zeroed.
__global__ __launch_bounds__(256)
void convert_kernel(const float* __restrict__ x, ushort_t* __restrict__ xb) {
    int id = blockIdx.x * 256 + threadIdx.x;      // 196608 = 256*6144/8
    int row = id / 768, c8 = id % 768;
    bf16x8 o = {};
    if (row < NN) {
        const float* p = x + (size_t)row * CC + c8 * 8;
        float4 a = *(const float4*)p, b = *(const float4*)(p + 4);
        o[0] = (short)f2bf(a.x); o[1] = (short)f2bf(a.y);
        o[2] = (short)f2bf(a.z); o[3] = (short)f2bf(a.w);
        o[4] = (short)f2bf(b.x); o[5] = (short)f2bf(b.y);
        o[6] = (short)f2bf(b.z); o[7] = (short)f2bf(b.w);
    }
    *(bf16x8*)(xb + (size_t)row * CC + c8 * 8) = o;
}

// qkv += 1 partial (in place, KS=2); emit bf16 Q (cols < 6144).
__global__ __launch_bounds__(256)
void reduce_qkv(float4* __restrict__ q4, const float4* __restrict__ p4,
                ushort_t* __restrict__ qb) {
    int i = blockIdx.x * 256 + threadIdx.x;     // 1,105,920 float4s
    float4 a = q4[i], b = p4[i];
    a.x += b.x; a.y += b.y; a.z += b.z; a.w += b.w;
    q4[i] = a;
    int row = i / 4608, c4 = i % 4608;
    if (c4 < 1536) {
        ushort4 u;
        u.x = f2bf(a.x); u.y = f2bf(a.y); u.z = f2bf(a.z); u.w = f2bf(a.w);
        *(ushort4*)(qb + (size_t)row * CC + c4 * 4) = u;
    }
}

// out += 7 partials (bias added by kc==0 epilogue)
__global__ __launch_bounds__(256)
void reduce_proj(float4* __restrict__ o4, const float4* __restrict__ p4,
                 long long s4) {
    int i = blockIdx.x * 256 + threadIdx.x;    // 368,640 float4s
    float4 a = o4[i];
#pragma unroll
    for (int k = 0; k < 7; ++k) {
        float4 b = p4[(size_t)k * s4 + i];
        a.x += b.x; a.y += b.y; a.z += b.z; a.w += b.w;
    }
    o4[i] = a;
}

// qmax[(h*240+n)*12 + c] = max over q[h][n][c*256 .. c*256+255]
__global__ __launch_bounds__(256)
void qmax_kernel(const float* __restrict__ qkv, float* __restrict__ qmax) {
    int idx = blockIdx.x * 4 + (threadIdx.x >> 6);   // 0..5759
    int lane = threadIdx.x & 63;
    int c = idx % 12;
    int r = idx / 12;            // h*240 + n
    int n = r % NN, h = r / NN;
    const float* p = qkv + (size_t)n * C3 + h * DD + c * 256 + lane * 4;
    float4 f = *(const float4*)p;
    float m = fmaxf(fmaxf(f.x, f.y), fmaxf(f.z, f.w));
#pragma unroll
    for (int off = 32; off >= 1; off >>= 1)
        m = fmaxf(m, __shfl_xor(m, off));
    if (lane == 0) qmax[idx] = m;
}

// Softmax rows of (scale * (attn + sum partials) + 0.1*Pq), in place.
__global__ __launch_bounds__(256)
void softmax_kernel(float* __restrict__ attn, const float* __restrict__ gpart,
                    int ksm1, const float* __restrict__ qmax) {
    int r = blockIdx.x * 4 + (threadIdx.x >> 6);   // 0..479 = z*240+n
    int lane = threadIdx.x & 63;
    int z = r / NN, n = r % NN;
    float* row = attn + (size_t)r * NN;
    const float* qm = qmax + r * 12;
    const float scale = 0.0180421959f;             // 3072^-0.5
    float v[4];
    float mx = -1e30f;
#pragma unroll
    for (int i = 0; i < 4; ++i) {
        int m = lane + 64 * i;
        v[i] = -1e30f;
        if (m < NN) {
            float s = row[m];
            for (int kc = 0; kc < ksm1; ++kc)
                s += gpart[(size_t)(z * ksm1 + kc) * (NN * NN)
                           + (size_t)n * NN + m];
            v[i] = s * scale + 0.1f * qm[m % 12];
        }
        mx = fmaxf(mx, v[i]);
    }
#pragma unroll
    for (int off = 32; off >= 1; off >>= 1)
        mx = fmaxf(mx, __shfl_xor(mx, off));
    float s = 0.f;
#pragma unroll
    for (int i = 0; i < 4; ++i) {
        v[i] = __expf(v[i] - mx);
        s += v[i];
    }
#pragma unroll
    for (int off = 32; off >= 1; off >>= 1)
        s += __shfl_xor(s, off);
    float inv = 1.0f / s;
#pragma unroll
    for (int i = 0; i < 4; ++i) {
        int m = lane + 64 * i;
        if (m < NN) row[m] = v[i] * inv;
    }
}

// preb[n][h*3072+dd] = bf16( sum_m attn[h][n][m] * v[h][m][dd] )
__global__ __launch_bounds__(256)
void pv_kernel(const float* __restrict__ attn, const float* __restrict__ qkv,
               ushort_t* __restrict__ preb) {
    const int h = blockIdx.z;
    const int n0 = blockIdx.y * 16;
    const int dd0 = blockIdx.x * 256;
    __shared__ float s_attn[16 * NN];
    for (int i = threadIdx.x; i < 16 * NN; i += 256)
        s_attn[i] = attn[(size_t)h * NN * NN + (n0 + i / NN) * NN + (i % NN)];
    __syncthreads();

    const float* vp = qkv + 2 * CC + h * DD + dd0 + threadIdx.x;
    float acc[16] = {};
    for (int m = 0; m < NN; m += 4) {
        float v0 = vp[(size_t)(m + 0) * C3];
        float v1 = vp[(size_t)(m + 1) * C3];
        float v2 = vp[(size_t)(m + 2) * C3];
        float v3 = vp[(size_t)(m + 3) * C3];
#pragma unroll
        for (int i = 0; i < 16; ++i) {
            float4 a = *(const float4*)&s_attn[i * NN + m];
            acc[i] += a.x * v0 + a.y * v1 + a.z * v2 + a.w * v3;
        }
    }
#pragma unroll
    for (int i = 0; i < 16; ++i)
        preb[(size_t)(n0 + i) * CC + h * DD + dd0 + threadIdx.x] =
            f2bf(acc[i]);
}

extern "C" void kernel_launch(void* const* d_in, const int* in_sizes, int n_in,
                              void* d_out, int out_size, void* d_ws, size_t ws_size,
                              hipStream_t stream) {
    const float* x      = (const float*)d_in[0];
    const float* w_qkv  = (const float*)d_in[1];
    const float* w_proj = (const float*)d_in[2];
    const float* b_proj = (const float*)d_in[3];
    float* out = (float*)d_out;

    // ws layout (floats): qkv 4.42M | attn 115K | qmax 5.8K |
    // xb,qb,preb (bf16 256x6144 each) | gpart 10.4M  => ~70 MB
    const size_t f_qkv  = (size_t)NN * C3;       // 4,423,680
    const size_t f_attn = (size_t)HH * NN * NN;
    const size_t f_qmax = (size_t)HH * NN * 12;
    const size_t f_pre  = (size_t)NN * CC;       // 1,474,560
    float* qkv   = (float*)d_ws;
    float* attn  = qkv + f_qkv;
    float* qmaxb = attn + f_attn;
    ushort_t* xb   = (ushort_t*)(qmaxb + f_qmax);
    ushort_t* qb   = xb + (size_t)256 * CC;
    ushort_t* preb = qb + (size_t)256 * CC;
    float* gpart = (float*)(preb + (size_t)256 * CC);

    // 0. bf16 conversion of x (zero-padded to 256 rows)
    convert_kernel<<<768, 256, 0, stream>>>(x, xb);

    // 1. qkv = x @ w_qkv^T  (KS=2, 576 blocks, Kc=3072, nt=96)
    gemm_m97<<<dim3(C3 / 64, 1, 2), 256, 0, stream>>>(
        xb, CC, 0LL, w_qkv, CC, 0LL, nullptr,
        qkv, 0LL, gpart, (long long)f_qkv,
        C3, C3, CC / 2, 2);
    reduce_qkv<<<4320, 256, 0, stream>>>((float4*)qkv, (const float4*)gpart, qb);

    // 2. Pq maxpool over q
    qmax_kernel<<<1440, 256, 0, stream>>>(qkv, qmaxb);

    // 3. attn_raw = Q @ K^T per head (KS=24, 192 blocks, Kc=128, nt=4)
    gemm_m97<<<dim3(4, 1, HH * 24), 256, 0, stream>>>(
        qb, CC, (long long)DD,
        qkv + CC, C3, (long long)DD, nullptr,
        attn, (long long)(NN * NN), gpart, (long long)(NN * NN),
        NN, NN, DD / 24, 24);

    // 4. softmax (fuses split-K reduce, scale, +0.1*Pq)
    softmax_kernel<<<120, 256, 0, stream>>>(attn, gpart, 23, qmaxb);

    // 5. preb = bf16(attn @ V)
    pv_kernel<<<dim3(12, 15, HH), 256, 0, stream>>>(attn, qkv, preb);

    // 6. out = pre @ w_proj^T + b_proj (KS=8, 768 blocks, Kc=768, nt=24)
    gemm_m97<<<dim3(CC / 64, 1, 8), 256, 0, stream>>>(
        preb, CC, 0LL, w_proj, CC, 0LL, b_proj,
        out, 0LL, gpart, (long long)f_pre,
        CC, CC, CC / 8, 8);
    reduce_proj<<<1440, 256, 0, stream>>>((float4*)out, (const float4*)gpart,
        (long long)(f_pre / 4));
}

// Round 12
// 350.858 us; speedup vs baseline: 1.4063x; 1.0518x over previous
//
#include <hip/hip_runtime.h>
#include <hip/hip_bf16.h>

// Problem constants
#define NN 240        // rows (tokens)
#define CC 6144       // channels
#define DD 3072       // head dim
#define C3 18432      // 3*C
#define HH 2          // heads

typedef __attribute__((ext_vector_type(8))) short bf16x8;
typedef __attribute__((ext_vector_type(4))) float f32x4;
typedef unsigned short ushort_t;

static __device__ __forceinline__ unsigned short f2bf(float f) {
    __hip_bfloat16 h = __float2bfloat16(f);
    return __builtin_bit_cast(unsigned short, h);
}

// global -> LDS direct DMA, 16 B per lane, LDS dest wave-uniform base.
#define GLDS16(g, l) __builtin_amdgcn_global_load_lds( \
    (const __attribute__((address_space(1))) void*)(g), \
    (__attribute__((address_space(3))) void*)(l), 16, 0, 0)

// ---------------------------------------------------------------------------
// gemm_pb ("page-burst"): C[240 x N] = A_bf16[256 x K] * B_fp32[N x K]^T.
// Attacks DRAM row-buffer thrash: B is fetched in 1-KB-PER-COLUMN bursts —
// one global_load_lds where all 64 lanes read one col's contiguous 1-KB
// k-slice (8 consecutive 128-B lines -> row hits), instead of 128-B touches
// spaced 24 KB apart (R2-R11, all ~0.9 TB/s).
// BM=256, BN=32, BK_outer=256, BK_inner=32. 256 threads (4 waves, wave =
// 64 rows x 32 cols, acc[4][2]). LDS: A [256][32]bf16 16 KB (R11 layout,
// restaged per inner step) + B [32 cols][256k]fp32 32 KB (staged once per
// 8 inner steps) = 48 KB -> 2 blocks/CU; co-resident block covers the
// B-transfer phase (m97/m114 mechanism). 2 barriers per inner step (R11).
// B LDS swizzle: 16B slot s of col c holds source slot s^(c&7) (involution,
// applied on the GLDS *source* address; reads XOR the same -> <=2-way).
// ---------------------------------------------------------------------------
__global__ __launch_bounds__(256, 2)
void gemm_pb(const ushort_t* __restrict__ Ab, int lda,
             const float* __restrict__ B, int ldb,
             const float* __restrict__ bias,
             float* __restrict__ C0,
             float* __restrict__ CP, long long sCPz,
             int ldc, int N, int Kc, int KS,
             ushort_t* __restrict__ Qb) {
    __shared__ ushort_t sA[256 * 32];   // 16 KB
    __shared__ float    sB[32 * 256];   // 32 KB  -> 48 KB total

    const int kc = blockIdx.z;
    const ushort_t* Abase = Ab + (size_t)kc * Kc;
    const float*    Bbase = B  + (size_t)kc * Kc;
    float* Cw = (kc == 0) ? C0 : (CP + (size_t)(kc - 1) * sCPz);

    const int n0 = blockIdx.x * 32;
    const int tid = threadIdx.x, lane = tid & 63, wid = tid >> 6;  // 4 waves
    const int l16 = lane & 15, lk = lane >> 4;

    // A staging (R11-proven): instr i covers rows (wid*4+i)*16..+15.
    // Lane l -> row +(l>>2), phys slot l&3 <- source k-oct (l&3)^((l>>3)&3).
    const int ar = lane >> 2;
    const int akoct = (lane & 3) ^ ((lane >> 3) & 3);

    const int nTot = Kc / 32;            // inner steps (32-k)
    f32x4 acc[4][2] = {};

    auto ISSUE_A = [&](int t32) {        // 4 GLDS/wave, stage current slice
#pragma unroll
        for (int i = 0; i < 4; ++i) {
            int rb = (wid * 4 + i) * 16;
            GLDS16(Abase + (size_t)(rb + ar) * lda + akoct * 8
                       + (size_t)t32 * 32,
                   sA + rb * 32);
        }
    };
    // B(T): 8 GLDS/wave; instr i = col c=wid*8+i, all 64 lanes read the
    // col's contiguous 1-KB slice (source slot lane^i, XOR low-3 bits).
    auto ISSUE_B = [&](int T) {
#pragma unroll
        for (int i = 0; i < 8; ++i) {
            int c = wid * 8 + i;         // c&7 == i (wid*8 is 8-aligned)
            const float* src = Bbase + (size_t)(n0 + c) * ldb
                               + (size_t)T * 256 + (lane ^ i) * 4;
            GLDS16(src, sB + c * 256);
        }
    };
    auto COMPUTE = [&](int s) {          // inner step s (0..7) of current T
        bf16x8 af[4];
#pragma unroll
        for (int mt = 0; mt < 4; ++mt) {
            int r = wid * 64 + mt * 16 + l16;
            af[mt] = *(const bf16x8*)((const char*)sA + r * 64
                        + ((lk ^ ((r >> 1) & 3)) * 16));
        }
#pragma unroll
        for (int nf = 0; nf < 2; ++nf) {
            int c = nf * 16 + l16;
            int j0 = (s * 8 + 2 * lk) ^ (c & 7);
            int j1 = (s * 8 + 2 * lk + 1) ^ (c & 7);
            f32x4 lo = *(const f32x4*)(sB + c * 256 + j0 * 4);
            f32x4 hi = *(const f32x4*)(sB + c * 256 + j1 * 4);
            bf16x8 r;
            r[0] = (short)f2bf(lo[0]); r[1] = (short)f2bf(lo[1]);
            r[2] = (short)f2bf(lo[2]); r[3] = (short)f2bf(lo[3]);
            r[4] = (short)f2bf(hi[0]); r[5] = (short)f2bf(hi[1]);
            r[6] = (short)f2bf(hi[2]); r[7] = (short)f2bf(hi[3]);
#pragma unroll
            for (int mt = 0; mt < 4; ++mt)
                acc[mt][nf] = __builtin_amdgcn_mfma_f32_16x16x32_bf16(
                    af[mt], r, acc[mt][nf], 0, 0, 0);
        }
    };

    ISSUE_B(0);                          // prologue: first B tile
    for (int t = 0; t < nTot; ++t) {
        ISSUE_A(t);
        __syncthreads();                 // compiler drain: A(t) (+B tile)
        COMPUTE(t & 7);
        __syncthreads();                 // protect sA (and sB at tile edge)
        if ((t & 7) == 7 && t + 1 < nTot)
            ISSUE_B((t >> 3) + 1);       // drained by next step's first sync
    }

    // Epilogue: fragment row = lk*4+j, col = nf*16 + l16
#pragma unroll
    for (int mt = 0; mt < 4; ++mt) {
#pragma unroll
        for (int j = 0; j < 4; ++j) {
            int grow = wid * 64 + mt * 16 + lk * 4 + j;
            if (grow < NN) {
#pragma unroll
                for (int nf = 0; nf < 2; ++nf) {
                    int gcol = n0 + nf * 16 + l16;
                    if (gcol < N) {
                        float v = acc[mt][nf][j];
                        if (kc == 0 && bias) v += bias[gcol];
                        Cw[(size_t)grow * ldc + gcol] = v;
                        if (Qb && gcol < CC)
                            Qb[(size_t)grow * CC + gcol] = f2bf(v);
                    }
                }
            }
        }
    }
}

// ---------------------------------------------------------------------------
// gemm_m97 (R11, proven): used for QK^T (small, L2-resident operands).
// ---------------------------------------------------------------------------
__global__ __launch_bounds__(256, 4)
void gemm_m97(const ushort_t* __restrict__ Ab, int lda, long long sAz,
              const float* __restrict__ B, int ldb, long long sBz,
              float* __restrict__ C0, long long sC0z,
              float* __restrict__ CP, long long sCPz,
              int ldc, int N, int Kc, int KS) {
    __shared__ ushort_t sA[256 * 32];   // 16 KB
    __shared__ float    sB[64 * 32];    //  8 KB

    const int zc = blockIdx.z;
    const int z = zc / KS, kc = zc % KS;
    const ushort_t* Abase = Ab + (size_t)z * sAz + (size_t)kc * Kc;
    const float*    Bbase = B  + (size_t)z * sBz + (size_t)kc * Kc;
    float* Cw = (kc == 0) ? (C0 + (size_t)z * sC0z)
                          : (CP + (size_t)(z * (KS - 1) + kc - 1) * sCPz);

    const int n0 = blockIdx.x * 64;
    const int tid = threadIdx.x, lane = tid & 63, wid = tid >> 6;
    const int l16 = lane & 15, lk = lane >> 4;

    const int ar = lane >> 2;
    const int akoct = (lane & 3) ^ ((lane >> 3) & 3);

    long long bofs[2];
#pragma unroll
    for (int i = 0; i < 2; ++i) {
        int cl = (wid * 2 + i) * 8 + (lane >> 3);
        int cg = n0 + cl; if (cg > N - 1) cg = N - 1;
        bofs[i] = (long long)cg * ldb + ((lane & 7) ^ ((lane >> 3) & 7)) * 4;
    }

    const int nt = Kc / 32;
    f32x4 acc[4][4] = {};

    for (int t = 0; t < nt; ++t) {
#pragma unroll
        for (int i = 0; i < 4; ++i) {
            int rb = (wid * 4 + i) * 16;
            GLDS16(Abase + (size_t)(rb + ar) * lda + akoct * 8 + (size_t)t * 32,
                   sA + rb * 32);
        }
#pragma unroll
        for (int i = 0; i < 2; ++i) {
            int cb = (wid * 2 + i) * 8;
            GLDS16(Bbase + bofs[i] + (size_t)t * 32, sB + cb * 32);
        }
        __syncthreads();

        bf16x8 af[4];
#pragma unroll
        for (int mt = 0; mt < 4; ++mt) {
            int r = wid * 64 + mt * 16 + l16;
            af[mt] = *(const bf16x8*)((const char*)sA + r * 64
                        + ((lk ^ ((r >> 1) & 3)) * 16));
        }
#pragma unroll
        for (int nf = 0; nf < 4; ++nf) {
            int c = nf * 16 + l16;
            const char* cb = (const char*)sB + c * 128;
            f32x4 lo = *(const f32x4*)(cb + (((2 * lk) ^ (c & 7)) * 16));
            f32x4 hi = *(const f32x4*)(cb + (((2 * lk + 1) ^ (c & 7)) * 16));
            bf16x8 r;
            r[0] = (short)f2bf(lo[0]); r[1] = (short)f2bf(lo[1]);
            r[2] = (short)f2bf(lo[2]); r[3] = (short)f2bf(lo[3]);
            r[4] = (short)f2bf(hi[0]); r[5] = (short)f2bf(hi[1]);
            r[6] = (short)f2bf(hi[2]); r[7] = (short)f2bf(hi[3]);
#pragma unroll
            for (int mt = 0; mt < 4; ++mt)
                acc[mt][nf] = __builtin_amdgcn_mfma_f32_16x16x32_bf16(
                    af[mt], r, acc[mt][nf], 0, 0, 0);
        }
        __syncthreads();
    }

#pragma unroll
    for (int mt = 0; mt < 4; ++mt) {
#pragma unroll
        for (int j = 0; j < 4; ++j) {
            int grow = wid * 64 + mt * 16 + lk * 4 + j;
            if (grow < NN) {
#pragma unroll
                for (int nf = 0; nf < 4; ++nf) {
                    int gcol = n0 + nf * 16 + l16;
                    if (gcol < N)
                        Cw[(size_t)grow * ldc + gcol] = acc[mt][nf][j];
                }
            }
        }
    }
}

// xb = bf16(x), rows 240..255 zeroed.
__global__ __launch_bounds__(256)
void convert_kernel(const float* __restrict__ x, ushort_t* __restrict__ xb) {
    int id = blockIdx.x * 256 + threadIdx.x;      // 196608 = 256*6144/8
    int row = id / 768, c8 = id % 768;
    bf16x8 o = {};
    if (row < NN) {
        const float* p = x + (size_t)row * CC + c8 * 8;
        float4 a = *(const float4*)p, b = *(const float4*)(p + 4);
        o[0] = (short)f2bf(a.x); o[1] = (short)f2bf(a.y);
        o[2] = (short)f2bf(a.z); o[3] = (short)f2bf(a.w);
        o[4] = (short)f2bf(b.x); o[5] = (short)f2bf(b.y);
        o[6] = (short)f2bf(b.z); o[7] = (short)f2bf(b.w);
    }
    *(bf16x8*)(xb + (size_t)row * CC + c8 * 8) = o;
}

// out += 3 partials (proj KS=4; bias added by kc==0 epilogue)
__global__ __launch_bounds__(256)
void reduce_proj(float4* __restrict__ o4, const float4* __restrict__ p4,
                 long long s4) {
    int i = blockIdx.x * 256 + threadIdx.x;    // 368,640 float4s
    float4 a = o4[i];
#pragma unroll
    for (int k = 0; k < 3; ++k) {
        float4 b = p4[(size_t)k * s4 + i];
        a.x += b.x; a.y += b.y; a.z += b.z; a.w += b.w;
    }
    o4[i] = a;
}

// qmax[(h*240+n)*12 + c] = max over q[h][n][c*256 .. c*256+255]
__global__ __launch_bounds__(256)
void qmax_kernel(const float* __restrict__ qkv, float* __restrict__ qmax) {
    int idx = blockIdx.x * 4 + (threadIdx.x >> 6);   // 0..5759
    int lane = threadIdx.x & 63;
    int c = idx % 12;
    int r = idx / 12;            // h*240 + n
    int n = r % NN, h = r / NN;
    const float* p = qkv + (size_t)n * C3 + h * DD + c * 256 + lane * 4;
    float4 f = *(const float4*)p;
    float m = fmaxf(fmaxf(f.x, f.y), fmaxf(f.z, f.w));
#pragma unroll
    for (int off = 32; off >= 1; off >>= 1)
        m = fmaxf(m, __shfl_xor(m, off));
    if (lane == 0) qmax[idx] = m;
}

// Softmax rows of (scale * (attn + sum partials) + 0.1*Pq), in place.
__global__ __launch_bounds__(256)
void softmax_kernel(float* __restrict__ attn, const float* __restrict__ gpart,
                    int ksm1, const float* __restrict__ qmax) {
    int r = blockIdx.x * 4 + (threadIdx.x >> 6);   // 0..479 = z*240+n
    int lane = threadIdx.x & 63;
    int z = r / NN, n = r % NN;
    float* row = attn + (size_t)r * NN;
    const float* qm = qmax + r * 12;
    const float scale = 0.0180421959f;             // 3072^-0.5
    float v[4];
    float mx = -1e30f;
#pragma unroll
    for (int i = 0; i < 4; ++i) {
        int m = lane + 64 * i;
        v[i] = -1e30f;
        if (m < NN) {
            float s = row[m];
            for (int kc = 0; kc < ksm1; ++kc)
                s += gpart[(size_t)(z * ksm1 + kc) * (NN * NN)
                           + (size_t)n * NN + m];
            v[i] = s * scale + 0.1f * qm[m % 12];
        }
        mx = fmaxf(mx, v[i]);
    }
#pragma unroll
    for (int off = 32; off >= 1; off >>= 1)
        mx = fmaxf(mx, __shfl_xor(mx, off));
    float s = 0.f;
#pragma unroll
    for (int i = 0; i < 4; ++i) {
        v[i] = __expf(v[i] - mx);
        s += v[i];
    }
#pragma unroll
    for (int off = 32; off >= 1; off >>= 1)
        s += __shfl_xor(s, off);
    float inv = 1.0f / s;
#pragma unroll
    for (int i = 0; i < 4; ++i) {
        int m = lane + 64 * i;
        if (m < NN) row[m] = v[i] * inv;
    }
}

// preb[n][h*3072+dd] = bf16( sum_m attn[h][n][m] * v[h][m][dd] )
__global__ __launch_bounds__(256)
void pv_kernel(const float* __restrict__ attn, const float* __restrict__ qkv,
               ushort_t* __restrict__ preb) {
    const int h = blockIdx.z;
    const int n0 = blockIdx.y * 16;
    const int dd0 = blockIdx.x * 256;
    __shared__ float s_attn[16 * NN];
    for (int i = threadIdx.x; i < 16 * NN; i += 256)
        s_attn[i] = attn[(size_t)h * NN * NN + (n0 + i / NN) * NN + (i % NN)];
    __syncthreads();

    const float* vp = qkv + 2 * CC + h * DD + dd0 + threadIdx.x;
    float acc[16] = {};
    for (int m = 0; m < NN; m += 4) {
        float v0 = vp[(size_t)(m + 0) * C3];
        float v1 = vp[(size_t)(m + 1) * C3];
        float v2 = vp[(size_t)(m + 2) * C3];
        float v3 = vp[(size_t)(m + 3) * C3];
#pragma unroll
        for (int i = 0; i < 16; ++i) {
            float4 a = *(const float4*)&s_attn[i * NN + m];
            acc[i] += a.x * v0 + a.y * v1 + a.z * v2 + a.w * v3;
        }
    }
#pragma unroll
    for (int i = 0; i < 16; ++i)
        preb[(size_t)(n0 + i) * CC + h * DD + dd0 + threadIdx.x] =
            f2bf(acc[i]);
}

extern "C" void kernel_launch(void* const* d_in, const int* in_sizes, int n_in,
                              void* d_out, int out_size, void* d_ws, size_t ws_size,
                              hipStream_t stream) {
    const float* x      = (const float*)d_in[0];
    const float* w_qkv  = (const float*)d_in[1];
    const float* w_proj = (const float*)d_in[2];
    const float* b_proj = (const float*)d_in[3];
    float* out = (float*)d_out;

    // ws layout (floats): qkv 4.42M | attn 115K | qmax 5.8K |
    // xb,qb,preb (bf16 256x6144 each) | gpart 10.4M  => ~70 MB
    const size_t f_qkv  = (size_t)NN * C3;       // 4,423,680
    const size_t f_attn = (size_t)HH * NN * NN;
    const size_t f_qmax = (size_t)HH * NN * 12;
    const size_t f_pre  = (size_t)NN * CC;       // 1,474,560
    float* qkv   = (float*)d_ws;
    float* attn  = qkv + f_qkv;
    float* qmaxb = attn + f_attn;
    ushort_t* xb   = (ushort_t*)(qmaxb + f_qmax);
    ushort_t* qb   = xb + (size_t)256 * CC;
    ushort_t* preb = qb + (size_t)256 * CC;
    float* gpart = (float*)(preb + (size_t)256 * CC);

    // 0. bf16 conversion of x (zero-padded to 256 rows)
    convert_kernel<<<768, 256, 0, stream>>>(x, xb);

    // 1. qkv = x @ w_qkv^T  (KS=1, 576 blocks; epilogue writes qkv + bf16 Q)
    gemm_pb<<<dim3(C3 / 32, 1, 1), 256, 0, stream>>>(
        xb, CC, w_qkv, CC, nullptr,
        qkv, nullptr, 0LL,
        C3, C3, CC, 1, qb);

    // 2. Pq maxpool over q
    qmax_kernel<<<1440, 256, 0, stream>>>(qkv, qmaxb);

    // 3. attn_raw = Q @ K^T per head (KS=24, 192 blocks, Kc=128, nt=4)
    gemm_m97<<<dim3(4, 1, HH * 24), 256, 0, stream>>>(
        qb, CC, (long long)DD,
        qkv + CC, C3, (long long)DD,
        attn, (long long)(NN * NN), gpart, (long long)(NN * NN),
        NN, NN, DD / 24, 24);

    // 4. softmax (fuses split-K reduce, scale, +0.1*Pq)
    softmax_kernel<<<120, 256, 0, stream>>>(attn, gpart, 23, qmaxb);

    // 5. preb = bf16(attn @ V)
    pv_kernel<<<dim3(12, 15, HH), 256, 0, stream>>>(attn, qkv, preb);

    // 6. out = pre @ w_proj^T + b_proj (KS=4, 768 blocks, Kc=1536)
    gemm_pb<<<dim3(CC / 32, 1, 4), 256, 0, stream>>>(
        preb, CC, w_proj, CC, b_proj,
        out, gpart, (long long)f_pre,
        CC, CC, CC / 4, 4, nullptr);
    reduce_proj<<<1440, 256, 0, stream>>>((float4*)out, (const float4*)gpart,
        (long long)(f_pre / 4));
}